// Round 3
// baseline (248.028 us; speedup 1.0000x reference)
//
#include <hip/hip_runtime.h>

// Problem constants (match reference)
#define BATCHN 32
#define NCELL  4096
#define BN     (BATCHN * NCELL)

// Round 3: wave-autonomous time blocking. No __syncthreads anywhere —
// round 1/2 were limited (~880 cyc/step) by the compiler's mandatory
// `s_waitcnt vmcnt(0)` before every s_barrier, which drained the per-step
// HBM trajectory store at every one of the 600 steps.
//
// Each WAVE owns OWN=128 cells + HALO=64 each side = 256 cells = 4/lane,
// all in registers. Halo exchange = 6 __shfl per step (no barrier, no LDS
// array). Stores are fire-and-forget for the whole 60-step launch.
constexpr int OWN    = 128;
constexpr int HALO   = 64;
constexpr int CPL    = 4;                  // cells per lane
constexpr int CELLS  = 64 * CPL;           // 256 = OWN + 2*HALO
constexpr int KSTEP  = 60;                 // steps per launch (< HALO)
constexpr int CHUNKS = NCELL / OWN;        // 32

// f(u) and |f'(u)| exactly as the reference's f_real + jvp derivative:
//   f  = 0.5*u*(3-u^2) + (10/12)*u^2*g,   g  = 0.75 - 2u + 1.5u^2 - 0.25u^4
//   f' = (1.5 - 1.5u^2) + (10/12)*(2u*g + u^2*g'),  g' = -2 + 3u - u^3
__device__ __forceinline__ void f_and_a(float u, float& f, float& a) {
    const float C56 = 0.8333333333333333f;  // 10/12 rounded to f32
    float u2 = u * u;
    float u4 = u2 * u2;
    float g  = 0.75f - 2.0f * u + 1.5f * u2 - 0.25f * u4;
    f = 0.5f * u * (3.0f - u2) + C56 * (u2 * g);
    float gp = -2.0f + 3.0f * u - u2 * u;
    float df = (1.5f - 1.5f * u2) + C56 * (2.0f * u * g + u2 * gp);
    a = fabsf(df);
}

__global__ __launch_bounds__(64) void lf_wave(const float* __restrict__ in_state,
                                              float* __restrict__ out,
                                              int s0, int nsteps) {
    const int lane  = threadIdx.x;          // 0..63, one wave per block
    const int wid   = blockIdx.x;           // 0..1023
    const int chunk = wid & (CHUNKS - 1);
    const int row   = wid >> 5;             // CHUNKS == 32
    const int gbase = chunk * OWN - HALO;   // local cell c -> global gbase + c
    const int c0    = lane * CPL;

    const float dtdx = (float)(0.0009 / (10.0 / 4096.0));

    // ---- load 4 cells/lane (clamped at physical edges) ----
    float u[CPL];
    {
        const float* ip = in_state + (size_t)row * NCELL;
        #pragma unroll
        for (int j = 0; j < CPL; ++j) {
            int g = gbase + c0 + j;
            g = min(max(g, 0), NCELL - 1);
            u[j] = ip[g];
        }
    }

    // owned cells are c in [HALO, HALO+OWN) = [64,192) -> lanes 16..47 (all 4 cells)
    const bool owned = (lane >= 16) && (lane < 48);
    const bool bcL = (chunk == 0) && (lane == 16);              // holds global cell 0
    const bool bcR = (chunk == CHUNKS - 1) && (lane == 47);     // holds global cell N-1

    float* op = out + (size_t)(s0 + 1) * BN + (size_t)row * NCELL + (gbase + c0);

    #pragma unroll 2
    for (int t = 0; t < nsteps; ++t) {
        float f[CPL], a[CPL];
        #pragma unroll
        for (int j = 0; j < CPL; ++j) f_and_a(u[j], f[j], a[j]);

        // halo exchange with neighbor lanes (wave-local, no barrier)
        float ul = __shfl_up(u[CPL - 1], 1);
        float fl = __shfl_up(f[CPL - 1], 1);
        float al = __shfl_up(a[CPL - 1], 1);
        float ur = __shfl_down(u[0], 1);
        float fr = __shfl_down(f[0], 1);
        float ar = __shfl_down(a[0], 1);
        // wave-edge clamp (matches cl=max(c-1,0)/cr=min(c+1,CELLS-1) of rounds 1-2)
        if (lane == 0)  { ul = u[0];        fl = f[0];        al = a[0]; }
        if (lane == 63) { ur = u[CPL - 1];  fr = f[CPL - 1];  ar = a[CPL - 1]; }

        // 5 interface fluxes (local LF)
        float fh[CPL + 1];
        fh[0] = 0.5f * (fl + f[0]) - 0.5f * fmaxf(al, a[0]) * (u[0] - ul);
        #pragma unroll
        for (int j = 1; j < CPL; ++j)
            fh[j] = 0.5f * (f[j - 1] + f[j]) - 0.5f * fmaxf(a[j - 1], a[j]) * (u[j] - u[j - 1]);
        fh[CPL] = 0.5f * (f[CPL - 1] + fr) - 0.5f * fmaxf(a[CPL - 1], ar) * (ur - u[CPL - 1]);

        float n[CPL];
        #pragma unroll
        for (int j = 0; j < CPL; ++j) n[j] = u[j] - dtdx * (fh[j + 1] - fh[j]);

        // outflow BCs: u[0]=u[1], u[N-1]=u[N-2] (firewall against halo garbage)
        if (bcL) n[0] = n[1];
        if (bcR) n[CPL - 1] = n[CPL - 2];

        if (owned) {
            *(float4*)op = make_float4(n[0], n[1], n[2], n[3]);
        }
        op += BN;

        #pragma unroll
        for (int j = 0; j < CPL; ++j) u[j] = n[j];
    }
}

extern "C" void kernel_launch(void* const* d_in, const int* in_sizes, int n_in,
                              void* d_out, int out_size, void* d_ws, size_t ws_size,
                              hipStream_t stream) {
    const float* init = (const float*)d_in[0];
    float* out = (float*)d_out;

    // stepnum is implied by out_size: (stepnum+1)*B*N elements
    const int total = out_size / BN - 1;

    // plane 0 = init
    hipMemcpyAsync(d_out, init, (size_t)BN * sizeof(float),
                   hipMemcpyDeviceToDevice, stream);

    const int nblocks = CHUNKS * BATCHN;    // 1024 waves, 4 per CU
    for (int s = 0; s < total; s += KSTEP) {
        int ns = (total - s) < KSTEP ? (total - s) : KSTEP;
        lf_wave<<<nblocks, 64, 0, stream>>>(out + (size_t)s * BN, out, s, ns);
    }
}

// Round 4
// 235.369 us; speedup vs baseline: 1.0538x; 1.0538x over previous
//
#include <hip/hip_runtime.h>

// Problem constants (match reference)
#define BATCHN 32
#define NCELL  4096
#define BN     (BATCHN * NCELL)

// Round 4: R3's wave-autonomous scheme + 4-deep store buffering.
// Theory: R1-R3 all cost ~800-900 cyc/step because each step's trajectory
// store forced a vmcnt wait (barrier drain in R1/R2; store-source register
// reuse in R3) exposing full store-commit latency at ~1 wave/SIMD.
// Fix: results of 4 consecutive steps go to dedicated register buffers
// (b0..b3) and are stored in a burst; buffers are rewritten only one group
// (~1000 cyc) later, so the implicit vmcnt wait finds stores retired.
constexpr int OWN    = 128;
constexpr int HALO   = 64;
constexpr int CPL    = 4;                  // cells per lane
constexpr int CELLS  = 64 * CPL;           // 256 = OWN + 2*HALO
constexpr int KSTEP  = 60;                 // steps per launch (< HALO)
constexpr int CHUNKS = NCELL / OWN;        // 32

// f(u) and |f'(u)| exactly as the reference's f_real + jvp derivative.
__device__ __forceinline__ void f_and_a(float u, float& f, float& a) {
    const float C56 = 0.8333333333333333f;  // 10/12 rounded to f32
    float u2 = u * u;
    float u4 = u2 * u2;
    float g  = 0.75f - 2.0f * u + 1.5f * u2 - 0.25f * u4;
    f = 0.5f * u * (3.0f - u2) + C56 * (u2 * g);
    float gp = -2.0f + 3.0f * u - u2 * u;
    float df = (1.5f - 1.5f * u2) + C56 * (2.0f * u * g + u2 * gp);
    a = fabsf(df);
}

// One LF step: u[] -> n[] (and u[] updated). Wave-local shfl halo exchange.
__device__ __forceinline__ void lf_step(float u[CPL], float n[CPL],
                                        int lane, bool bcL, bool bcR,
                                        float dtdx) {
    float f[CPL], a[CPL];
    #pragma unroll
    for (int j = 0; j < CPL; ++j) f_and_a(u[j], f[j], a[j]);

    float ul = __shfl_up(u[CPL - 1], 1);
    float fl = __shfl_up(f[CPL - 1], 1);
    float al = __shfl_up(a[CPL - 1], 1);
    float ur = __shfl_down(u[0], 1);
    float fr = __shfl_down(f[0], 1);
    float ar = __shfl_down(a[0], 1);
    if (lane == 0)  { ul = u[0];        fl = f[0];        al = a[0]; }
    if (lane == 63) { ur = u[CPL - 1];  fr = f[CPL - 1];  ar = a[CPL - 1]; }

    float fh[CPL + 1];
    fh[0] = 0.5f * (fl + f[0]) - 0.5f * fmaxf(al, a[0]) * (u[0] - ul);
    #pragma unroll
    for (int j = 1; j < CPL; ++j)
        fh[j] = 0.5f * (f[j - 1] + f[j]) - 0.5f * fmaxf(a[j - 1], a[j]) * (u[j] - u[j - 1]);
    fh[CPL] = 0.5f * (f[CPL - 1] + fr) - 0.5f * fmaxf(a[CPL - 1], ar) * (ur - u[CPL - 1]);

    #pragma unroll
    for (int j = 0; j < CPL; ++j) n[j] = u[j] - dtdx * (fh[j + 1] - fh[j]);

    // outflow BCs: u[0]=u[1], u[N-1]=u[N-2] (firewall against halo garbage)
    if (bcL) n[0] = n[1];
    if (bcR) n[CPL - 1] = n[CPL - 2];

    #pragma unroll
    for (int j = 0; j < CPL; ++j) u[j] = n[j];
}

__global__ __launch_bounds__(64) void lf_wave(const float* __restrict__ in_state,
                                              float* __restrict__ out,
                                              int s0, int nsteps) {
    const int lane  = threadIdx.x;          // one wave per block
    const int wid   = blockIdx.x;
    const int chunk = wid & (CHUNKS - 1);
    const int row   = wid >> 5;             // CHUNKS == 32
    const int gbase = chunk * OWN - HALO;
    const int c0    = lane * CPL;

    const float dtdx = (float)(0.0009 / (10.0 / 4096.0));

    float u[CPL];
    {
        const float* ip = in_state + (size_t)row * NCELL;
        #pragma unroll
        for (int j = 0; j < CPL; ++j) {
            int g = gbase + c0 + j;
            g = min(max(g, 0), NCELL - 1);
            u[j] = ip[g];
        }
    }

    // owned cells [64,192) -> lanes 16..47 (all 4 cells contiguous)
    const bool owned = (lane >= 16) && (lane < 48);
    const bool bcL = (chunk == 0) && (lane == 16);
    const bool bcR = (chunk == CHUNKS - 1) && (lane == 47);

    float* op = out + (size_t)(s0 + 1) * BN + (size_t)row * NCELL + (gbase + c0);

    int t = 0;
    // main body: groups of 4 steps, stores batched per group so the store
    // data registers (b0..b3) have a full group (~1000 cyc) to drain before
    // reuse -> no exposed store-completion stall.
    for (; t + 4 <= nsteps; t += 4) {
        float b0[CPL], b1[CPL], b2[CPL], b3[CPL];
        lf_step(u, b0, lane, bcL, bcR, dtdx);
        lf_step(u, b1, lane, bcL, bcR, dtdx);
        lf_step(u, b2, lane, bcL, bcR, dtdx);
        lf_step(u, b3, lane, bcL, bcR, dtdx);
        if (owned) {
            *(float4*)(op)            = make_float4(b0[0], b0[1], b0[2], b0[3]);
            *(float4*)(op + BN)       = make_float4(b1[0], b1[1], b1[2], b1[3]);
            *(float4*)(op + 2 * BN)   = make_float4(b2[0], b2[1], b2[2], b2[3]);
            *(float4*)(op + 3 * BN)   = make_float4(b3[0], b3[1], b3[2], b3[3]);
        }
        op += 4 * BN;
    }
    // tail (not hit for nsteps=60, kept for robustness)
    for (; t < nsteps; ++t) {
        float n[CPL];
        lf_step(u, n, lane, bcL, bcR, dtdx);
        if (owned) *(float4*)op = make_float4(n[0], n[1], n[2], n[3]);
        op += BN;
    }
}

extern "C" void kernel_launch(void* const* d_in, const int* in_sizes, int n_in,
                              void* d_out, int out_size, void* d_ws, size_t ws_size,
                              hipStream_t stream) {
    const float* init = (const float*)d_in[0];
    float* out = (float*)d_out;

    const int total = out_size / BN - 1;

    // plane 0 = init
    hipMemcpyAsync(d_out, init, (size_t)BN * sizeof(float),
                   hipMemcpyDeviceToDevice, stream);

    const int nblocks = CHUNKS * BATCHN;    // 1024 waves
    for (int s = 0; s < total; s += KSTEP) {
        int ns = (total - s) < KSTEP ? (total - s) : KSTEP;
        lf_wave<<<nblocks, 64, 0, stream>>>(out + (size_t)s * BN, out, s, ns);
    }
}